// Round 9
// baseline (139.552 us; speedup 1.0000x reference)
//
#include <hip/hip_runtime.h>

// Problem constants (from reference)
#define N_NODES 100000
#define N_EDGES 1600000
#define D_IN    50
#define HIDDEN  128
#define NCLS    8

// Bucket-sort parameters
#define TILE    4096
#define NTILES  ((N_EDGES + TILE - 1) / TILE)   // 391
#define BSHIFT  9
#define NB      196                              // ceil(100000 / 512)

// LDS row stride (dwords) for padded bf16 weight rows: 128 bf16 + 8 pad = 136 bf16
#define LW 68

typedef __bf16 bf16_t;
typedef bf16_t bf16x8 __attribute__((ext_vector_type(8)));
typedef float  f32x4  __attribute__((ext_vector_type(4)));
typedef float  f32x2v __attribute__((ext_vector_type(2)));

// ---------------------------------------------------------------------------
// Helpers: bf16 pack/unpack (RNE)
// ---------------------------------------------------------------------------
__device__ __forceinline__ unsigned f2bf(float f) {
    union { float f; unsigned u; } a; a.f = f;
    unsigned u = a.u;
    return (u + 0x7FFFu + ((u >> 16) & 1u)) >> 16;
}
__device__ __forceinline__ unsigned pack2(float a, float b) {
    return f2bf(a) | (f2bf(b) << 16);
}
__device__ __forceinline__ float bf_lo(unsigned v) { return __uint_as_float(v << 16); }
__device__ __forceinline__ float bf_hi(unsigned v) { return __uint_as_float(v & 0xFFFF0000u); }

// ===========================================================================
// conv_x: xb8[n][16] dwords = 50 fp8 e4m3 + pad (one 64B line per row);
// Acat x-part (cols 50..99 bf16) + zero pad.
// t = n*32 + j.
// ===========================================================================
__global__ __launch_bounds__(256) void conv_x_kernel(
    const float* __restrict__ x, unsigned* __restrict__ xb8,
    unsigned* __restrict__ acat)
{
    int t = blockIdx.x * 256 + threadIdx.x;
    if (t >= N_NODES * 32) return;
    int n = t >> 5, j = t & 31;
    const float2* x2 = (const float2*)x;
    if (j < 25) {
        float2 v = x2[n * 25 + j];
        acat[(size_t)n * 64 + 25 + j] = pack2(v.x, v.y);
    } else {
        int z = n * 64 + 50 + (j - 25) * 2;
        acat[z] = 0u;
        acat[z + 1] = 0u;
    }
    if (j < 13) {
        // fp8 dword j = features 4j..4j+3
        float2 u0 = x2[n * 25 + 2 * j];
        float2 u1 = (j < 12) ? x2[n * 25 + 2 * j + 1] : make_float2(0.f, 0.f);
        int w = __builtin_amdgcn_cvt_pk_fp8_f32(u0.x, u0.y, 0, false);
        w = __builtin_amdgcn_cvt_pk_fp8_f32(u1.x, u1.y, w, true);
        xb8[n * 16 + j] = (unsigned)w;
    } else if (j >= 25 && j < 28) {
        xb8[n * 16 + 13 + (j - 25)] = 0u;
    }
}

// ===========================================================================
// conv_w: W1cat^T [128][128] bf16 and W2cat^T [16][128] bf16
// ===========================================================================
__global__ __launch_bounds__(256) void conv_w_kernel(
    const float* __restrict__ W1l, const float* __restrict__ W1r,
    const float* __restrict__ W2l, const float* __restrict__ W2r,
    unsigned* __restrict__ Wt1g, unsigned* __restrict__ W2tg)
{
    int t = blockIdx.x * 256 + threadIdx.x;
    if (t < 8192) {
        int n = t >> 6, kp = t & 63;
        int k0 = kp * 2, k1 = k0 + 1;
        float v0 = (k0 < 50) ? W1l[k0 * 128 + n] : ((k0 < 100) ? W1r[(k0 - 50) * 128 + n] : 0.0f);
        float v1 = (k1 < 50) ? W1l[k1 * 128 + n] : ((k1 < 100) ? W1r[(k1 - 50) * 128 + n] : 0.0f);
        Wt1g[t] = pack2(v0, v1);
    } else if (t < 8192 + 1024) {
        int u = t - 8192;
        int n2 = u >> 6, kp = u & 63;
        int k0 = kp * 2;
        float v0 = (n2 < 8) ? W2l[k0 * 8 + n2] : W2r[k0 * 8 + n2 - 8];
        float v1 = (n2 < 8) ? W2l[(k0 + 1) * 8 + n2] : W2r[(k0 + 1) * 8 + n2 - 8];
        W2tg[u] = pack2(v0, v1);
    }
}

// ===========================================================================
// passA: per-tile bucket histogram (LDS atomics), g_hist[tile][NB]
// ===========================================================================
__global__ __launch_bounds__(256) void passA_kernel(
    const int* __restrict__ dst, int* __restrict__ g_hist)
{
    __shared__ int lh[NB];
    int tid = threadIdx.x;
    for (int i = tid; i < NB; i += 256) lh[i] = 0;
    __syncthreads();
    int base = blockIdx.x * TILE;
    int cnt = min(TILE, N_EDGES - base);
    for (int i = tid; i < cnt; i += 256)
        atomicAdd(&lh[dst[base + i] >> BSHIFT], 1);
    __syncthreads();
    for (int i = tid; i < NB; i += 256) g_hist[blockIdx.x * NB + i] = lh[i];
}

// ===========================================================================
// passB: per-bucket exclusive scan over tiles; btot[b] = bucket total
// ===========================================================================
__global__ __launch_bounds__(512) void passB_kernel(
    int* __restrict__ g_hist, int* __restrict__ btot)
{
    __shared__ int s[512];
    int b = blockIdx.x, tid = threadIdx.x;
    int v = (tid < NTILES) ? g_hist[tid * NB + b] : 0;
    s[tid] = v;
    __syncthreads();
    for (int d = 1; d < 512; d <<= 1) {
        int t = (tid >= d) ? s[tid - d] : 0;
        __syncthreads();
        s[tid] += t;
        __syncthreads();
    }
    if (tid < NTILES) g_hist[tid * NB + b] = s[tid] - v;
    if (tid == 511) btot[b] = s[511];
}

// ===========================================================================
// passB2: exclusive scan of btot -> bbase; sentinel offs[N] = E
// ===========================================================================
__global__ __launch_bounds__(256) void passB2_kernel(
    const int* __restrict__ btot, int* __restrict__ bbase, int* __restrict__ offs)
{
    __shared__ int s[256];
    int tid = threadIdx.x;
    int v = (tid < NB) ? btot[tid] : 0;
    s[tid] = v;
    __syncthreads();
    for (int d = 1; d < 256; d <<= 1) {
        int t = (tid >= d) ? s[tid - d] : 0;
        __syncthreads();
        s[tid] += t;
        __syncthreads();
    }
    if (tid < NB) bbase[tid] = s[tid] - v;
    if (tid == 0) offs[N_NODES] = N_EDGES;
}

// ===========================================================================
// passC: reorder tile by bucket in LDS; flush PACKED edges
// (src in bits 0..16, dst_local in bits 17..25) to bk_pack.
// ===========================================================================
__global__ __launch_bounds__(256) void passC_kernel(
    const int* __restrict__ src, const int* __restrict__ dst,
    const int* __restrict__ g_hist, const int* __restrict__ bbase,
    unsigned* __restrict__ bk_pack)
{
    __shared__ int hist[NB];
    __shared__ int seg[NB];
    __shared__ int cur[NB];
    __shared__ int gof[NB];
    __shared__ int sc[256];
    __shared__ unsigned s_pack[TILE];
    __shared__ unsigned short s_bkt[TILE];

    int tid = threadIdx.x, tile = blockIdx.x;
    int base = tile * TILE;
    int cnt = min(TILE, N_EDGES - base);

    for (int i = tid; i < NB; i += 256) {
        hist[i] = 0;
        gof[i] = g_hist[tile * NB + i] + bbase[i];
    }
    __syncthreads();

    int es[16], ed[16];
    #pragma unroll
    for (int k = 0; k < 16; ++k) {
        int i = tid + k * 256;
        if (i < cnt) {
            es[k] = src[base + i];
            ed[k] = dst[base + i];
            atomicAdd(&hist[ed[k] >> BSHIFT], 1);
        }
    }
    __syncthreads();

    {
        int v = (tid < NB) ? hist[tid] : 0;
        sc[tid] = v;
        __syncthreads();
        for (int d = 1; d < 256; d <<= 1) {
            int t = (tid >= d) ? sc[tid - d] : 0;
            __syncthreads();
            sc[tid] += t;
            __syncthreads();
        }
        if (tid < NB) { seg[tid] = sc[tid] - v; cur[tid] = sc[tid] - v; }
    }
    __syncthreads();

    #pragma unroll
    for (int k = 0; k < 16; ++k) {
        int i = tid + k * 256;
        if (i < cnt) {
            int b = ed[k] >> BSHIFT;
            int p = atomicAdd(&cur[b], 1);
            s_pack[p] = (unsigned)es[k] | ((unsigned)(ed[k] & 511) << 17);
            s_bkt[p] = (unsigned short)b;
        }
    }
    __syncthreads();

    for (int i = tid; i < cnt; i += 256) {
        int b = s_bkt[i];
        int g = gof[b] + (i - seg[b]);
        bk_pack[g] = s_pack[i];
    }
}

// ===========================================================================
// passD: per-bucket CSR finalize from packed edges
// ===========================================================================
__global__ __launch_bounds__(512) void passD_kernel(
    const unsigned* __restrict__ bk_pack,
    const int* __restrict__ bbase, const int* __restrict__ btot,
    int* __restrict__ sorted_src, int* __restrict__ offs)
{
    __shared__ int ldeg[512];
    __shared__ int lofs[512];
    int b = blockIdx.x, tid = threadIdx.x;
    int ebase = bbase[b];
    int ecnt = btot[b];
    int nbase = b << BSHIFT;

    ldeg[tid] = 0;
    __syncthreads();
    for (int i = tid; i < ecnt; i += 512)
        atomicAdd(&ldeg[bk_pack[ebase + i] >> 17], 1);
    __syncthreads();

    int v = ldeg[tid];
    lofs[tid] = v;
    __syncthreads();
    for (int d = 1; d < 512; d <<= 1) {
        int t = (tid >= d) ? lofs[tid - d] : 0;
        __syncthreads();
        lofs[tid] += t;
        __syncthreads();
    }
    int ex = lofs[tid] - v;

    int node = nbase + tid;
    if (node < N_NODES) offs[node] = ebase + ex;

    ldeg[tid] = ex;
    __syncthreads();
    for (int i = tid; i < ecnt; i += 512) {
        unsigned pk = bk_pack[ebase + i];
        int p = atomicAdd(&ldeg[pk >> 17], 1);
        sorted_src[ebase + p] = (int)(pk & 0x1FFFFu);
    }
}

// ===========================================================================
// Gather-aggregate fp8 x rows (one 64B line per edge). One node per
// half-wave; 2 edge-slots x 16 dwords per half-wave; 8-deep unroll ->
// 16 lines in flight per half-wave. HW fp8->f32 decode.
// ===========================================================================
#define ACC8(a, v) { f32x2v lo_ = __builtin_amdgcn_cvt_pk_f32_fp8((v), false); \
                     f32x2v hi_ = __builtin_amdgcn_cvt_pk_f32_fp8((v), true);  \
                     a.x += lo_[0]; a.y += lo_[1]; a.z += hi_[0]; a.w += hi_[1]; }

__global__ __launch_bounds__(256) void agg_x_kernel(
    const unsigned* __restrict__ xb8,
    const int*      __restrict__ offs,
    const int*      __restrict__ ss,
    unsigned* __restrict__ acat)
{
    int node = blockIdx.x * 8 + (threadIdx.x >> 5);
    int l32  = threadIdx.x & 31;
    int slot = l32 >> 4;      // 0..1 (edge slot)
    int dw   = l32 & 15;      // 0..15 (dword within 64B row)
    if (node >= N_NODES) return;
    int beg = offs[node], end = offs[node + 1];
    float4 a0 = {0,0,0,0}, a1 = {0,0,0,0}, a2 = {0,0,0,0}, a3 = {0,0,0,0};
    float4 a4 = {0,0,0,0}, a5 = {0,0,0,0}, a6 = {0,0,0,0}, a7 = {0,0,0,0};
    int i = beg;
    for (; i + 15 < end; i += 16) {
        int s0 = ss[i + slot];
        int s1 = ss[i + slot + 2];
        int s2 = ss[i + slot + 4];
        int s3 = ss[i + slot + 6];
        int s4 = ss[i + slot + 8];
        int s5 = ss[i + slot + 10];
        int s6 = ss[i + slot + 12];
        int s7 = ss[i + slot + 14];
        unsigned v0 = xb8[s0 * 16 + dw];
        unsigned v1 = xb8[s1 * 16 + dw];
        unsigned v2 = xb8[s2 * 16 + dw];
        unsigned v3 = xb8[s3 * 16 + dw];
        unsigned v4 = xb8[s4 * 16 + dw];
        unsigned v5 = xb8[s5 * 16 + dw];
        unsigned v6 = xb8[s6 * 16 + dw];
        unsigned v7 = xb8[s7 * 16 + dw];
        ACC8(a0, v0); ACC8(a1, v1); ACC8(a2, v2); ACC8(a3, v3);
        ACC8(a4, v4); ACC8(a5, v5); ACC8(a6, v6); ACC8(a7, v7);
    }
    for (; i + 1 < end; i += 2) {
        unsigned v = xb8[ss[i + slot] * 16 + dw];
        ACC8(a0, v);
    }
    if (i < end && slot == 0) {
        unsigned v = xb8[ss[i] * 16 + dw];
        ACC8(a0, v);
    }
    float4 t;
    t.x = ((a0.x + a1.x) + (a2.x + a3.x)) + ((a4.x + a5.x) + (a6.x + a7.x));
    t.y = ((a0.y + a1.y) + (a2.y + a3.y)) + ((a4.y + a5.y) + (a6.y + a7.y));
    t.z = ((a0.z + a1.z) + (a2.z + a3.z)) + ((a4.z + a5.z) + (a6.z + a7.z));
    t.w = ((a0.w + a1.w) + (a2.w + a3.w)) + ((a4.w + a5.w) + (a6.w + a7.w));
    t.x += __shfl_xor(t.x, 16);
    t.y += __shfl_xor(t.y, 16);
    t.z += __shfl_xor(t.z, 16);
    t.w += __shfl_xor(t.w, 16);
    if (slot == 0 && dw < 13) {
        float inv = 1.0f / fmaxf((float)(end - beg), 1.0f);
        if (dw < 12) {
            uint2 o;
            o.x = pack2(t.x * inv, t.y * inv);
            o.y = pack2(t.z * inv, t.w * inv);
            *((uint2*)(acat + (size_t)node * 64 + dw * 2)) = o;
        } else {
            acat[(size_t)node * 64 + 24] = pack2(t.x * inv, t.y * inv);
        }
    }
}

// ===========================================================================
// Fused MLP: h = relu(Acat @ W1cat + b1) via MFMA (swapped operands), then
// p = bf16(h@W2l), q = h@W2r + b2 via a second MFMA pass through LDS.
// ===========================================================================
__global__ __launch_bounds__(256) void fused_mlp_kernel(
    const unsigned* __restrict__ Acat,   // [N][64] dwords (128 bf16)
    const unsigned* __restrict__ Wt1g,   // [128][64] dwords
    const unsigned* __restrict__ W2tg,   // [16][64] dwords
    const float* __restrict__ b1,
    const float* __restrict__ b2,
    unsigned* __restrict__ pb,           // [N][4] dwords (8 bf16)
    float* __restrict__ q)               // [N][8]
{
    __shared__ unsigned sWt[128 * LW];
    __shared__ unsigned sW2t[16 * LW];
    __shared__ bf16_t   sH[4][16 * 136];

    int tid = threadIdx.x;
    for (int t = tid; t < 128 * 64; t += 256)
        sWt[(t >> 6) * LW + (t & 63)] = Wt1g[t];
    for (int t = tid; t < 16 * 64; t += 256)
        sW2t[(t >> 6) * LW + (t & 63)] = W2tg[t];
    __syncthreads();

    const int w    = tid >> 6;
    const int lane = tid & 63;
    const int lo   = lane & 15;
    const int g    = lane >> 4;

    float b1v[8][4];
    #pragma unroll
    for (int nt = 0; nt < 8; ++nt)
        #pragma unroll
        for (int r = 0; r < 4; ++r)
            b1v[nt][r] = b1[nt * 16 + g * 4 + r];
    float b2v[4];
    #pragma unroll
    for (int r = 0; r < 4; ++r)
        b2v[r] = (g >= 2) ? b2[(g - 2) * 4 + r] : 0.0f;

    bf16_t* myH = &sH[w][0];

    for (int tile = blockIdx.x; tile * 64 < N_NODES; tile += gridDim.x) {
        int node = tile * 64 + w * 16 + lo;
        int nclamp = min(node, N_NODES - 1);

        int4 bi[4];
        #pragma unroll
        for (int ks = 0; ks < 4; ++ks)
            bi[ks] = *((const int4*)(Acat + (size_t)nclamp * 64 + ks * 16 + g * 4));

        f32x4 acc[8];
        #pragma unroll
        for (int nt = 0; nt < 8; ++nt) acc[nt] = (f32x4)0.0f;
        #pragma unroll
        for (int nt = 0; nt < 8; ++nt) {
            #pragma unroll
            for (int ks = 0; ks < 4; ++ks) {
                int4 ai = *((const int4*)(sWt + (nt * 16 + lo) * LW + ks * 16 + g * 4));
                acc[nt] = __builtin_amdgcn_mfma_f32_16x16x32_bf16(
                    __builtin_bit_cast(bf16x8, ai),
                    __builtin_bit_cast(bf16x8, bi[ks]), acc[nt], 0, 0, 0);
            }
        }

        #pragma unroll
        for (int nt = 0; nt < 8; ++nt) {
            union { bf16_t h[4]; uint2 u; } pk;
            #pragma unroll
            for (int r = 0; r < 4; ++r)
                pk.h[r] = (bf16_t)fmaxf(acc[nt][r] + b1v[nt][r], 0.0f);
            *((uint2*)(myH + lo * 136 + nt * 16 + g * 4)) = pk.u;
        }
        __syncthreads();

        f32x4 acc2 = (f32x4)0.0f;
        #pragma unroll
        for (int ks = 0; ks < 4; ++ks) {
            int4 a2 = *((const int4*)(sW2t + lo * LW + ks * 16 + g * 4));
            int4 h2 = *((const int4*)(myH + lo * 136 + ks * 32 + g * 8));
            acc2 = __builtin_amdgcn_mfma_f32_16x16x32_bf16(
                __builtin_bit_cast(bf16x8, a2),
                __builtin_bit_cast(bf16x8, h2), acc2, 0, 0, 0);
        }

        if (node < N_NODES) {
            if (g < 2) {
                union { bf16_t h[4]; uint2 u; } pk;
                #pragma unroll
                for (int r = 0; r < 4; ++r) pk.h[r] = (bf16_t)acc2[r];
                *((uint2*)(pb + (size_t)node * 4 + g * 2)) = pk.u;
            } else {
                float4 qq;
                qq.x = acc2[0] + b2v[0];
                qq.y = acc2[1] + b2v[1];
                qq.z = acc2[2] + b2v[2];
                qq.w = acc2[3] + b2v[3];
                *((float4*)(q + (size_t)node * 8 + (g - 2) * 4)) = qq;
            }
        }
        __syncthreads();
    }
}

// ===========================================================================
// Gather-aggregate bf16 p rows + final: out = (sum p[src]) / max(deg,1) + q
// ===========================================================================
__global__ __launch_bounds__(256) void aggp_final_kernel(
    const unsigned* __restrict__ pb,   // [N][4] dwords (8 bf16)
    const float*    __restrict__ q,
    const int*      __restrict__ offs,
    const int*      __restrict__ ss,
    float* __restrict__ out)
{
    int node = blockIdx.x * 4 + (threadIdx.x >> 6);
    int lane = threadIdx.x & 63;
    int k  = lane >> 2;
    int c2 = lane & 3;
    if (node >= N_NODES) return;
    int beg = offs[node], end = offs[node + 1];
    float2 acc = make_float2(0.0f, 0.0f);
    int i = beg + k;
    int sNext = (i < end) ? ss[i] : 0;
    for (; i < end; i += 16) {
        int s = sNext;
        int i2 = i + 16;
        sNext = (i2 < end) ? ss[i2] : 0;
        unsigned v = pb[s * 4 + c2];
        acc.x += bf_lo(v);
        acc.y += bf_hi(v);
    }
    acc.x += __shfl_xor(acc.x, 4);  acc.y += __shfl_xor(acc.y, 4);
    acc.x += __shfl_xor(acc.x, 8);  acc.y += __shfl_xor(acc.y, 8);
    acc.x += __shfl_xor(acc.x, 16); acc.y += __shfl_xor(acc.y, 16);
    acc.x += __shfl_xor(acc.x, 32); acc.y += __shfl_xor(acc.y, 32);
    if (lane < 4) {
        float inv = 1.0f / fmaxf((float)(end - beg), 1.0f);
        float2 qq = ((const float2*)(q + (size_t)node * NCLS))[c2];
        ((float2*)(out + (size_t)node * NCLS))[c2] =
            make_float2(acc.x * inv + qq.x, acc.y * inv + qq.y);
    }
}

// ===========================================================================
extern "C" void kernel_launch(void* const* d_in, const int* in_sizes, int n_in,
                              void* d_out, int out_size, void* d_ws, size_t ws_size,
                              hipStream_t stream)
{
    const float* x   = (const float*)d_in[0];
    const int*   ei  = (const int*)  d_in[1];
    const float* W1l = (const float*)d_in[2];
    const float* W1r = (const float*)d_in[3];
    const float* b1  = (const float*)d_in[4];
    const float* W2l = (const float*)d_in[5];
    const float* W2r = (const float*)d_in[6];
    const float* b2  = (const float*)d_in[7];
    float* out = (float*)d_out;

    const int* src = ei;
    const int* dst = ei + N_EDGES;

    // Workspace layout (dword units; all segment sizes are multiples of 4)
    int* ws = (int*)d_ws;
    int*      offs       = ws;                                   // 100004
    int*      g_hist     = offs + (N_NODES + 4);                 // 76636
    int*      btot       = g_hist + NTILES * NB;                 // 256
    int*      bbase      = btot + 256;                           // 256
    int*      sorted_src = bbase + 256;                          // E
    unsigned* xb8        = (unsigned*)(sorted_src + N_EDGES);    // N*16 (64B rows)
    unsigned* Acat       = xb8 + (size_t)N_NODES * 16;           // N*64
    unsigned* Wt1g       = Acat + (size_t)N_NODES * 64;          // 8192
    unsigned* W2tg       = Wt1g + 8192;                          // 1024
    unsigned* pb         = W2tg + 1024;                          // N*4
    float*    q          = (float*)(pb + (size_t)N_NODES * 4);   // N*8
    unsigned* bk_pack    = (unsigned*)(q + (size_t)N_NODES * 8); // E

    conv_x_kernel<<<(N_NODES * 32 + 255) / 256, 256, 0, stream>>>(x, xb8, Acat);
    conv_w_kernel<<<36, 256, 0, stream>>>(W1l, W1r, W2l, W2r, Wt1g, W2tg);

    // CSR build via two-level bucket sort (packed edge records)
    passA_kernel <<<NTILES, 256, 0, stream>>>(dst, g_hist);
    passB_kernel <<<NB, 512, 0, stream>>>(g_hist, btot);
    passB2_kernel<<<1, 256, 0, stream>>>(btot, bbase, offs);
    passC_kernel <<<NTILES, 256, 0, stream>>>(src, dst, g_hist, bbase, bk_pack);
    passD_kernel <<<NB, 512, 0, stream>>>(bk_pack, bbase, btot, sorted_src, offs);

    // Layer 1 aggregation (writes Acat cols 0..49)
    agg_x_kernel<<<(N_NODES + 7) / 8, 256, 0, stream>>>(xb8, offs, sorted_src, Acat);

    // Fused layer1 GEMM + relu + layer2 GEMMs (h stays on-chip)
    fused_mlp_kernel<<<512, 256, 0, stream>>>(Acat, Wt1g, W2tg, b1, b2, pb, q);

    // Layer 2 aggregation + final
    aggp_final_kernel<<<(N_NODES + 3) / 4, 256, 0, stream>>>(
        (const unsigned*)pb, q, offs, sorted_src, out);
}